// Round 1
// baseline (399.168 us; speedup 1.0000x reference)
//
#include <hip/hip_runtime.h>

#define B_  64
#define H_  32
#define D_  4096
#define KD  128
#define VD  128
#define M_  4095
#define M1_ 4096
#define LOG2E 1.44269504088896f

// ---- workspace layout (float offsets) ----
// P      : reusable partial region, max 32 MiB (8,388,608 floats)
// q      : B*H*KD = 262,144
// logits : B*H*M1 = 8,388,608
// mstats : 2048*2 = 4,096
// o      : B*H*VD = 262,144
#define WS_P      0ull
#define WS_Q      8388608ull
#define WS_LOGITS 8650752ull
#define WS_MSTATS 17039360ull
#define WS_O      17043456ull
// total = 17,305,600 floats = 69.2 MB

// ---------------- K1a: partial projections (q, k_new, v_new) ----------------
// grid (16 d-chunks, 34 hx) ; hx<32 -> Wq[h], hx==32 -> Wk, hx==33 -> Wv
__global__ __launch_bounds__(256) void k_proj_partial(
    const float* __restrict__ x, const float* __restrict__ Wq,
    const float* __restrict__ Wk, const float* __restrict__ Wv,
    float* __restrict__ P) {
  __shared__ float xs[64][256];   // 64 KB
  const int dc = blockIdx.x;      // 0..15
  const int hx = blockIdx.y;      // 0..33
  const int t  = threadIdx.x;
  const float* xsrc = x + dc * 256;
  #pragma unroll
  for (int j = 0; j < 16; ++j) {
    int f = t + 256 * j;          // f4 index 0..4095
    int row = f >> 6, c4 = f & 63;
    *(float4*)&xs[row][c4 * 4] =
        *(const float4*)(xsrc + (size_t)row * D_ + c4 * 4);
  }
  __syncthreads();
  const int bq = t >> 4;          // 0..15 (4 b each)
  const int kg = t & 15;          // 0..15 (8 k each)
  const int b0 = bq * 4;
  const float* W = (hx < H_) ? (Wq + (size_t)hx * D_ * KD)
                             : ((hx == H_) ? Wk : Wv);
  const float* wp = W + (size_t)(dc * 256) * KD + kg * 8;
  float acc[4][8];
  #pragma unroll
  for (int i = 0; i < 4; ++i)
    #pragma unroll
    for (int j = 0; j < 8; ++j) acc[i][j] = 0.f;
  #pragma unroll 2
  for (int d = 0; d < 256; ++d) {
    float4 w0 = *(const float4*)(wp + (size_t)d * KD);
    float4 w1 = *(const float4*)(wp + (size_t)d * KD + 4);
    float xv[4];
    #pragma unroll
    for (int i = 0; i < 4; ++i) xv[i] = xs[b0 + i][d];
    #pragma unroll
    for (int i = 0; i < 4; ++i) {
      acc[i][0] += xv[i] * w0.x; acc[i][1] += xv[i] * w0.y;
      acc[i][2] += xv[i] * w0.z; acc[i][3] += xv[i] * w0.w;
      acc[i][4] += xv[i] * w1.x; acc[i][5] += xv[i] * w1.y;
      acc[i][6] += xv[i] * w1.z; acc[i][7] += xv[i] * w1.w;
    }
  }
  #pragma unroll
  for (int i = 0; i < 4; ++i) {
    size_t base = ((size_t)(dc * 64 + b0 + i) * 34 + hx) * KD + kg * 8;
    *(float4*)&P[base]     = make_float4(acc[i][0], acc[i][1], acc[i][2], acc[i][3]);
    *(float4*)&P[base + 4] = make_float4(acc[i][4], acc[i][5], acc[i][6], acc[i][7]);
  }
}

// ---------------- K1b: reduce partials -> q, Kc[.,M,:], Vc[.,M,:] ----------
__global__ __launch_bounds__(256) void k_proj_reduce(
    const float* __restrict__ P, float* __restrict__ q,
    float* __restrict__ Kc, float* __restrict__ Vc) {
  int i = blockIdx.x * 256 + threadIdx.x;  // < 64*34*128 = 278528
  int k = i & 127;
  int hx = (i >> 7) % 34;
  int b = i / (128 * 34);
  float s = 0.f;
  #pragma unroll
  for (int dc = 0; dc < 16; ++dc)
    s += P[(size_t)dc * (64 * 34 * 128) + (size_t)(b * 34 + hx) * 128 + k];
  if (hx < H_)       q[((size_t)b * H_ + hx) * KD + k] = s;
  else if (hx == H_) Kc[((size_t)b * M1_ + M_) * KD + k] = s;
  else               Vc[((size_t)b * M1_ + M_) * VD + k] = s;
}

// ---------------- K2: copy prev_K -> Kc fused with logits = q.K^T ----------
// grid (64 m-chunks of 64, 64 b)
__global__ __launch_bounds__(256) void k_logits(
    const float* __restrict__ prevK, const float* __restrict__ q,
    float* __restrict__ Kc, float* __restrict__ logits) {
  __shared__ float qs[32][132];   // padded: +4 floats
  __shared__ float ks[64][132];
  const int chunk = blockIdx.x;
  const int b = blockIdx.y;
  const int t = threadIdx.x;
  const int m0 = chunk * 64;
  const float* qsrc = q + (size_t)b * H_ * KD;
  #pragma unroll
  for (int j = 0; j < 4; ++j) {
    int f = t + 256 * j;          // 0..1023 (32 rows x 32 f4)
    int row = f >> 5, c4 = f & 31;
    *(float4*)&qs[row][c4 * 4] =
        *(const float4*)(qsrc + (size_t)row * KD + c4 * 4);
  }
  #pragma unroll
  for (int j = 0; j < 8; ++j) {
    int f = t + 256 * j;          // 0..2047 (64 rows x 32 f4)
    int r = f >> 5, c4 = f & 31;
    int m = m0 + r;
    float4 v;
    if (m < M_) v = *(const float4*)(prevK + ((size_t)b * M_ + m) * KD + c4 * 4);
    else        v = *(const float4*)(Kc + ((size_t)b * M1_ + M_) * KD + c4 * 4);
    *(float4*)&ks[r][c4 * 4] = v;
    if (m < M_) *(float4*)(Kc + ((size_t)b * M1_ + m) * KD + c4 * 4) = v;
  }
  __syncthreads();
  const int hg = t >> 4;          // 0..15 (2 h each)
  const int mg = t & 15;          // 0..15 (4 m each, strided by 16)
  const int h0 = hg * 2;
  float acc[2][4];
  #pragma unroll
  for (int hi = 0; hi < 2; ++hi)
    #pragma unroll
    for (int i = 0; i < 4; ++i) acc[hi][i] = 0.f;
  #pragma unroll 2
  for (int k4 = 0; k4 < 32; ++k4) {
    float4 qa = *(const float4*)&qs[h0][k4 * 4];
    float4 qb = *(const float4*)&qs[h0 + 1][k4 * 4];
    float4 kv[4];
    #pragma unroll
    for (int i = 0; i < 4; ++i) kv[i] = *(const float4*)&ks[mg + i * 16][k4 * 4];
    #pragma unroll
    for (int i = 0; i < 4; ++i) {
      acc[0][i] += qa.x * kv[i].x + qa.y * kv[i].y + qa.z * kv[i].z + qa.w * kv[i].w;
      acc[1][i] += qb.x * kv[i].x + qb.y * kv[i].y + qb.z * kv[i].z + qb.w * kv[i].w;
    }
  }
  #pragma unroll
  for (int hi = 0; hi < 2; ++hi)
    #pragma unroll
    for (int i = 0; i < 4; ++i)
      logits[(size_t)(b * H_ + h0 + hi) * M1_ + m0 + mg + i * 16] = acc[hi][i];
}

// ---------------- K3: per-row max and 1/sum(exp) ---------------------------
__global__ __launch_bounds__(256) void k_rowstats(
    const float* __restrict__ logits, float* __restrict__ mstats) {
  const int bh = blockIdx.x;
  const int t = threadIdx.x;
  const float4* row = (const float4*)(logits + (size_t)bh * M1_);
  float4 v[4];
  float mx = -3.402823466e38f;
  #pragma unroll
  for (int j = 0; j < 4; ++j) {
    v[j] = row[t + 256 * j];
    mx = fmaxf(mx, fmaxf(fmaxf(v[j].x, v[j].y), fmaxf(v[j].z, v[j].w)));
  }
  #pragma unroll
  for (int off = 32; off >= 1; off >>= 1) mx = fmaxf(mx, __shfl_xor(mx, off));
  __shared__ float redm[4], reds[4];
  int wave = t >> 6, lane = t & 63;
  if (lane == 0) redm[wave] = mx;
  __syncthreads();
  mx = fmaxf(fmaxf(redm[0], redm[1]), fmaxf(redm[2], redm[3]));
  float s = 0.f;
  #pragma unroll
  for (int j = 0; j < 4; ++j) {
    s += exp2f((v[j].x - mx) * LOG2E) + exp2f((v[j].y - mx) * LOG2E)
       + exp2f((v[j].z - mx) * LOG2E) + exp2f((v[j].w - mx) * LOG2E);
  }
  #pragma unroll
  for (int off = 32; off >= 1; off >>= 1) s += __shfl_xor(s, off);
  if (lane == 0) reds[wave] = s;
  __syncthreads();
  if (t == 0) {
    s = reds[0] + reds[1] + reds[2] + reds[3];
    mstats[bh * 2] = mx;
    mstats[bh * 2 + 1] = 1.0f / s;
  }
}

// ---------------- K4: copy prev_V -> Vc fused with partial o = w.V ---------
// grid (32 m-chunks of 128, 64 b); two 64-row staging halves
__global__ __launch_bounds__(256) void k_attnv(
    const float* __restrict__ prevV, const float* __restrict__ logits,
    const float* __restrict__ mstats, float* __restrict__ Vc,
    float* __restrict__ Po) {
  __shared__ float vs[64][128];   // 32 KB
  __shared__ float wsm[128][36];  // transposed weights [m][h], 18 KB
  __shared__ float ms[64];
  const int chunk = blockIdx.x;   // 0..31
  const int b = blockIdx.y;
  const int t = threadIdx.x;
  const int m0 = chunk * 128;
  if (t < 64) ms[t] = mstats[b * 64 + t];
  __syncthreads();
  #pragma unroll
  for (int j = 0; j < 4; ++j) {
    int f = t + 256 * j;          // 0..1023 f4 over [32 h][32 m4]
    int h = f >> 5, m4 = f & 31;
    float4 l = *(const float4*)(logits + (size_t)(b * H_ + h) * M1_ + m0 + m4 * 4);
    float mx = ms[2 * h], inv = ms[2 * h + 1];
    wsm[m4 * 4 + 0][h] = exp2f((l.x - mx) * LOG2E) * inv;
    wsm[m4 * 4 + 1][h] = exp2f((l.y - mx) * LOG2E) * inv;
    wsm[m4 * 4 + 2][h] = exp2f((l.z - mx) * LOG2E) * inv;
    wsm[m4 * 4 + 3][h] = exp2f((l.w - mx) * LOG2E) * inv;
  }
  const int hg = t >> 5;          // 0..7  (4 h each)
  const int vg = t & 31;          // 0..31 (4 v each)
  const int h0 = hg * 4, v0 = vg * 4;
  float acc[4][4];
  #pragma unroll
  for (int hi = 0; hi < 4; ++hi)
    #pragma unroll
    for (int vi = 0; vi < 4; ++vi) acc[hi][vi] = 0.f;
  for (int half = 0; half < 2; ++half) {
    __syncthreads();   // wsm ready / previous compute done
    #pragma unroll
    for (int j = 0; j < 8; ++j) {
      int f = t + 256 * j; int r = f >> 5, c4 = f & 31;
      int m = m0 + half * 64 + r;
      float4 v;
      if (m < M_) v = *(const float4*)(prevV + ((size_t)b * M_ + m) * VD + c4 * 4);
      else        v = *(const float4*)(Vc + ((size_t)b * M1_ + M_) * VD + c4 * 4);
      *(float4*)&vs[r][c4 * 4] = v;
      if (m < M_) *(float4*)(Vc + ((size_t)b * M1_ + m) * VD + c4 * 4) = v;
    }
    __syncthreads();
    #pragma unroll 4
    for (int mm = 0; mm < 64; ++mm) {
      int m = half * 64 + mm;
      float4 w4 = *(const float4*)&wsm[m][h0];
      float4 v4 = *(const float4*)&vs[mm][v0];
      float wv[4] = {w4.x, w4.y, w4.z, w4.w};
      float vv[4] = {v4.x, v4.y, v4.z, v4.w};
      #pragma unroll
      for (int hi = 0; hi < 4; ++hi)
        #pragma unroll
        for (int vi = 0; vi < 4; ++vi) acc[hi][vi] += wv[hi] * vv[vi];
    }
  }
  #pragma unroll
  for (int hi = 0; hi < 4; ++hi) {
    size_t base = ((size_t)(chunk * 64 + b) * H_ + h0 + hi) * VD + v0;
    *(float4*)&Po[base] = make_float4(acc[hi][0], acc[hi][1], acc[hi][2], acc[hi][3]);
  }
}

// ---------------- K4b: reduce partial o ------------------------------------
__global__ __launch_bounds__(256) void k_oreduce(
    const float* __restrict__ Po, float* __restrict__ o) {
  int i = blockIdx.x * 256 + threadIdx.x;  // < 262144
  float s = 0.f;
  #pragma unroll
  for (int c = 0; c < 32; ++c) s += Po[(size_t)c * 262144 + i];
  o[i] = s;
}

// ---------------- K5: partial y = o . Wo -----------------------------------
// grid (32 d-chunks of 128, 16 hv-chunks of 256)
__global__ __launch_bounds__(256) void k_out_partial(
    const float* __restrict__ o, const float* __restrict__ Wo,
    float* __restrict__ Py) {
  __shared__ float os[64][256];   // 64 KB
  const int dc = blockIdx.x;      // 0..31
  const int hvc = blockIdx.y;     // 0..15
  const int t = threadIdx.x;
  #pragma unroll
  for (int j = 0; j < 16; ++j) {
    int f = t + 256 * j;          // 0..4095 f4 over [64][64]
    int row = f >> 6, c4 = f & 63;
    *(float4*)&os[row][c4 * 4] =
        *(const float4*)(o + (size_t)row * 4096 + hvc * 256 + c4 * 4);
  }
  __syncthreads();
  const int bq = t >> 4, dg = t & 15;
  const int b0 = bq * 4;
  const float* wp = Wo + (size_t)(hvc * 256) * D_ + dc * 128 + dg * 8;
  float acc[4][8];
  #pragma unroll
  for (int i = 0; i < 4; ++i)
    #pragma unroll
    for (int j = 0; j < 8; ++j) acc[i][j] = 0.f;
  #pragma unroll 2
  for (int hv = 0; hv < 256; ++hv) {
    float4 w0 = *(const float4*)(wp + (size_t)hv * D_);
    float4 w1 = *(const float4*)(wp + (size_t)hv * D_ + 4);
    float ov[4];
    #pragma unroll
    for (int i = 0; i < 4; ++i) ov[i] = os[b0 + i][hv];
    #pragma unroll
    for (int i = 0; i < 4; ++i) {
      acc[i][0] += ov[i] * w0.x; acc[i][1] += ov[i] * w0.y;
      acc[i][2] += ov[i] * w0.z; acc[i][3] += ov[i] * w0.w;
      acc[i][4] += ov[i] * w1.x; acc[i][5] += ov[i] * w1.y;
      acc[i][6] += ov[i] * w1.z; acc[i][7] += ov[i] * w1.w;
    }
  }
  #pragma unroll
  for (int i = 0; i < 4; ++i) {
    size_t base = ((size_t)hvc * 64 + b0 + i) * 4096 + dc * 128 + dg * 8;
    *(float4*)&Py[base]     = make_float4(acc[i][0], acc[i][1], acc[i][2], acc[i][3]);
    *(float4*)&Py[base + 4] = make_float4(acc[i][4], acc[i][5], acc[i][6], acc[i][7]);
  }
}

// ---------------- K5b: reduce partial y ------------------------------------
__global__ __launch_bounds__(256) void k_yreduce(
    const float* __restrict__ Py, float* __restrict__ y) {
  int i = blockIdx.x * 256 + threadIdx.x;  // < 262144
  float s = 0.f;
  #pragma unroll
  for (int c = 0; c < 16; ++c) s += Py[(size_t)c * 262144 + i];
  y[i] = s;
}

extern "C" void kernel_launch(void* const* d_in, const int* in_sizes, int n_in,
                              void* d_out, int out_size, void* d_ws, size_t ws_size,
                              hipStream_t stream) {
  const float* x     = (const float*)d_in[0];
  const float* prevK = (const float*)d_in[1];
  const float* prevV = (const float*)d_in[2];
  const float* Wq    = (const float*)d_in[3];
  const float* Wk    = (const float*)d_in[4];
  const float* Wv    = (const float*)d_in[5];
  const float* Wo    = (const float*)d_in[6];

  float* y  = (float*)d_out;                 // [64][4096]
  float* Kc = y + (size_t)B_ * D_;           // [64][4096][128]
  float* Vc = Kc + (size_t)B_ * M1_ * KD;    // [64][4096][128]

  float* ws     = (float*)d_ws;
  float* P      = ws + WS_P;
  float* q      = ws + WS_Q;
  float* logits = ws + WS_LOGITS;
  float* mstats = ws + WS_MSTATS;
  float* o      = ws + WS_O;

  k_proj_partial<<<dim3(16, 34), 256, 0, stream>>>(x, Wq, Wk, Wv, P);
  k_proj_reduce<<<1088, 256, 0, stream>>>(P, q, Kc, Vc);
  k_logits<<<dim3(64, 64), 256, 0, stream>>>(prevK, q, Kc, logits);
  k_rowstats<<<2048, 256, 0, stream>>>(logits, mstats);
  k_attnv<<<dim3(32, 64), 256, 0, stream>>>(prevV, logits, mstats, Vc, P);
  k_oreduce<<<1024, 256, 0, stream>>>(P, o);
  k_out_partial<<<dim3(32, 16), 256, 0, stream>>>(o, Wo, P);
  k_yreduce<<<1024, 256, 0, stream>>>(P, y);
}